// Round 10
// baseline (397.972 us; speedup 1.0000x reference)
//
#include <hip/hip_runtime.h>

#define NB   4
#define C_IN 256
#define CQD  64
#define NPT  4096
#define L2E  1.44269504088896f

typedef __attribute__((ext_vector_type(8)))  short bf16x8;
typedef __attribute__((ext_vector_type(4)))  float f32x4;
typedef __attribute__((ext_vector_type(16))) float f32x16;
typedef unsigned short u16;
typedef unsigned int   u32;

#define EXP2F(x)        __builtin_amdgcn_exp2f(x)
#define MFMA32(A,B,C)   __builtin_amdgcn_mfma_f32_16x16x32_bf16(A,B,C,0,0,0)
#define MFMA3216(A,B,C) __builtin_amdgcn_mfma_f32_32x32x16_bf16(A,B,C,0,0,0)

__device__ __forceinline__ u16 f2bf(float f) {          // RNE (cold paths)
    u32 u = __float_as_uint(f);
    u += 0x7fff + ((u >> 16) & 1);
    return (u16)(u >> 16);
}
// one v_perm: (bf16_trunc(hi)<<16) | bf16_trunc(lo)
__device__ __forceinline__ u32 pack_trunc(float lo, float hi) {
    return __builtin_amdgcn_perm(__float_as_uint(hi), __float_as_uint(lo), 0x07060302u);
}

// ---------------------------------------------------------------------------
// prep: pack wq|wk|wv into bf16 wbf[384][256]; q rows scaled by qscale.
// ---------------------------------------------------------------------------
__global__ void prep_kernel(
    const float* __restrict__ wq, const float* __restrict__ bq,
    const float* __restrict__ wk, const float* __restrict__ bk,
    const float* __restrict__ wv, const float* __restrict__ bv,
    u16* __restrict__ wbf, float* __restrict__ bias, float qscale)
{
    const int gid = blockIdx.x*256 + threadIdx.x;
    if (gid < 384*256) {
        const int r = gid >> 8, c = gid & 255;
        float v = (r < 64) ? wq[r*256 + c] * qscale
                : (r < 128) ? wk[(r-64)*256 + c]
                            : wv[(r-128)*256 + c];
        wbf[gid] = f2bf(v);
    } else if (gid < 384*256 + 384) {
        const int r = gid - 384*256;
        bias[r] = (r < 64) ? bq[r]*qscale : (r < 128) ? bk[r-64] : bv[r-128];
    }
}

// ---------------------------------------------------------------------------
// proj: MFMA pointwise projections, x read ONCE. 512-thread blocks.
// grid (N/32, B), block 512.
// ---------------------------------------------------------------------------
union ProjShared {
    u16 x_t[32][264];
    struct { u16 qk[32][136]; u16 vl[256][40]; } ep;
};

__global__ __launch_bounds__(512) void proj_kernel(
    const float* __restrict__ x, const u16* __restrict__ wbf,
    const float* __restrict__ bias,
    u16* __restrict__ qT, u16* __restrict__ kT, u16* __restrict__ vbf)
{
    __shared__ ProjShared sh;

    const int t  = threadIdx.x;
    const int n0 = blockIdx.x * 32;
    const int b  = blockIdx.y;

    {
        const int ln = t & 31;
        const int cg = t >> 5;
        #pragma unroll
        for (int rr = 0; rr < 4; rr++) {
            const int c = 4*cg + 64*rr;
            const float f0 = x[((size_t)(b*C_IN + c+0))*NPT + n0 + ln];
            const float f1 = x[((size_t)(b*C_IN + c+1))*NPT + n0 + ln];
            const float f2 = x[((size_t)(b*C_IN + c+2))*NPT + n0 + ln];
            const float f3 = x[((size_t)(b*C_IN + c+3))*NPT + n0 + ln];
            ushort4 u4;
            u4.x = f2bf(f0); u4.y = f2bf(f1); u4.z = f2bf(f2); u4.w = f2bf(f3);
            *(ushort4*)&sh.x_t[ln][c] = u4;
        }
    }
    __syncthreads();

    const int w = t >> 6, l = t & 63, q = l >> 4, c16 = l & 15;

    f32x4 acc[3][2];
    #pragma unroll
    for (int ot = 0; ot < 3; ot++)
        #pragma unroll
        for (int nt = 0; nt < 2; nt++)
            acc[ot][nt] = (f32x4){0.f, 0.f, 0.f, 0.f};

    #pragma unroll
    for (int kk = 0; kk < 8; kk++) {
        const bf16x8 bf0 = *(const bf16x8*)&sh.x_t[c16     ][kk*32 + 8*q];
        const bf16x8 bf1 = *(const bf16x8*)&sh.x_t[16 + c16][kk*32 + 8*q];
        #pragma unroll
        for (int ot = 0; ot < 3; ot++) {
            const int o = 16*(8*ot + w) + c16;
            const bf16x8 af = *(const bf16x8*)&wbf[(size_t)o*C_IN + kk*32 + 8*q];
            acc[ot][0] = MFMA32(af, bf0, acc[ot][0]);
            acc[ot][1] = MFMA32(af, bf1, acc[ot][1]);
        }
    }
    __syncthreads();

    #pragma unroll
    for (int ot = 0; ot < 3; ot++) {
        const int T  = 8*ot + w;
        const int ob = 16*T + 4*q;
        float b0 = bias[ob+0], b1 = bias[ob+1], b2 = bias[ob+2], b3 = bias[ob+3];
        #pragma unroll
        for (int nt = 0; nt < 2; nt++) {
            const f32x4 a = acc[ot][nt];
            const float v0 = a[0]+b0, v1 = a[1]+b1, v2 = a[2]+b2, v3 = a[3]+b3;
            if (ot == 0) {
                uint2 u;
                u.x = (u32)f2bf(v0) | ((u32)f2bf(v1) << 16);
                u.y = (u32)f2bf(v2) | ((u32)f2bf(v3) << 16);
                *(uint2*)&sh.ep.qk[16*nt + c16][ob] = u;
            } else {
                const int cb = 16*T - 128 + 4*q;
                sh.ep.vl[cb+0][16*nt + c16] = f2bf(v0);
                sh.ep.vl[cb+1][16*nt + c16] = f2bf(v1);
                sh.ep.vl[cb+2][16*nt + c16] = f2bf(v2);
                sh.ep.vl[cb+3][16*nt + c16] = f2bf(v3);
            }
        }
    }
    __syncthreads();

    {
        const int n  = t >> 4;
        const int o8 = (t & 15) * 8;
        const uint4 qkv = *(uint4*)&sh.ep.qk[n][o8];
        if (o8 < 64)
            *(uint4*)&qT[((size_t)b*NPT + n0 + n)*CQD + o8] = qkv;
        else
            *(uint4*)&kT[((size_t)b*NPT + n0 + n)*CQD + (o8 - 64)] = qkv;

        const int c = t >> 1, hf = (t & 1) * 16;
        u16* vrow = &vbf[((size_t)b*C_IN + c)*NPT + n0 + hf];
        *(uint4*)&vrow[0] = *(uint4*)&sh.ep.vl[c][hf];
        *(uint4*)&vrow[8] = *(uint4*)&sh.ep.vl[c][hf + 8];
    }
}

// ===========================================================================
// SPLIT PATH: score -> iZ -> vn -> PV   (p^T materialized, stats eliminated)
// ===========================================================================

// score: s once (q prescaled by L2E). u = exp2(s'), write pT[b][m][n] bf16,
// accumulate complete row sums into Zpart[b][ms][n]. Wave = 32 n x 512 m
// sweep; no barriers (per-wave LDS transpose region, wave-synchronous).
// grid 1024 flat (b=id&3), block 256.
__global__ __launch_bounds__(256, 4) void score_kernel(
    const u16* __restrict__ qT, const u16* __restrict__ kT,
    float* __restrict__ Zpart, u16* __restrict__ pT)
{
    __shared__ uint2 stage[4][640];   // per wave: 64 m-rows x 10-unit stride

    const int t = threadIdx.x;
    const int w = t >> 6, l = t & 63, l5 = l >> 5, lm = l & 31;
    const int id = blockIdx.x;
    const int b  = id & 3;
    const int ms = (id >> 2) & 7;
    const int nb = id >> 5;           // 0..31
    const int n0 = nb*128 + w*32;

    // q A-frags for this wave's 32 n-rows (whole kernel)
    bf16x8 qa[4];
    #pragma unroll
    for (int ks = 0; ks < 4; ks++)
        qa[ks] = *(const bf16x8*)&qT[((size_t)b*NPT + n0 + lm)*CQD + 16*ks + 8*l5];

    float zacc[16];
    #pragma unroll
    for (int r = 0; r < 16; r++) zacc[r] = 0.f;

    for (int it = 0; it < 8; it++) {
        const int mb = ms*512 + it*64;

        f32x16 sacc[2];
        #pragma unroll
        for (int mj = 0; mj < 2; mj++) {
            #pragma unroll
            for (int r = 0; r < 16; r++) sacc[mj][r] = 0.f;
            #pragma unroll
            for (int ks = 0; ks < 4; ks++) {
                const bf16x8 kf = *(const bf16x8*)
                    &kT[((size_t)b*NPT + mb + 32*mj + lm)*CQD + 16*ks + 8*l5];
                sacc[mj] = MFMA3216(qa[ks], kf, sacc[mj]);
            }
        }

        // u = exp2(s'), Z accumulate, stage transposed units
        #pragma unroll
        for (int mj = 0; mj < 2; mj++) {
            #pragma unroll
            for (int g = 0; g < 4; g++) {
                const float u0 = EXP2F(sacc[mj][4*g+0]);
                const float u1 = EXP2F(sacc[mj][4*g+1]);
                const float u2 = EXP2F(sacc[mj][4*g+2]);
                const float u3 = EXP2F(sacc[mj][4*g+3]);
                zacc[4*g+0] += u0; zacc[4*g+1] += u1;
                zacc[4*g+2] += u2; zacc[4*g+3] += u3;
                uint2 uu;
                uu.x = pack_trunc(u0, u1);
                uu.y = pack_trunc(u2, u3);
                stage[w][(mj*32 + lm)*10 + 2*g + l5] = uu;
            }
        }
        __asm__ volatile("s_waitcnt lgkmcnt(0)" ::: "memory");

        // copy out: lane l -> m-row mb+l, 4 x 16B chunks of 32 n
        #pragma unroll
        for (int c = 0; c < 4; c++) {
            const uint4 d = *(const uint4*)&stage[w][l*10 + 2*c];
            *(uint4*)&pT[((size_t)b*NPT + mb + l)*NPT + n0 + 8*c] = d;
        }
    }

    // reduce Z over the 32 m-lanes (butterfly stays within 32-halves)
    #pragma unroll
    for (int r = 0; r < 16; r++) {
        #pragma unroll
        for (int d = 1; d < 32; d <<= 1)
            zacc[r] += __shfl_xor(zacc[r], d, 64);
    }
    if (lm == 0) {
        #pragma unroll
        for (int r = 0; r < 16; r++) {
            const int n = n0 + (r & 3) + 8*(r >> 2) + 4*l5;
            Zpart[((size_t)(b*8 + ms))*NPT + n] = zacc[r];
        }
    }
}

// iZ[b][n] = gamma / sum_ms Zpart
__global__ void iz_kernel(const float* __restrict__ Zpart,
                          const float* __restrict__ gamma, float* __restrict__ iZ)
{
    const int g = blockIdx.x*256 + threadIdx.x;   // 0..16383
    const int b = g >> 12, n = g & 4095;
    float Z = 0.f;
    #pragma unroll
    for (int s = 0; s < 8; s++) Z += Zpart[((size_t)(b*8 + s))*NPT + n];
    iZ[g] = gamma[0] / Z;
}

// vn[c][n] = bf16( v[c][n] * iZ[n] )   (gamma+normalization folded into v)
__global__ __launch_bounds__(256) void vn_kernel(
    const u16* __restrict__ vbf, const float* __restrict__ iZ, u16* __restrict__ vn)
{
    const int id = blockIdx.x;          // 0..1023
    const int b = id & 3, c = id >> 2;
    const int t = threadIdx.x;
    const size_t base = ((size_t)(b*C_IN + c))*NPT + t*16;
    const uint4 a0 = *(const uint4*)&vbf[base];
    const uint4 a1 = *(const uint4*)&vbf[base + 8];
    const float* zp = &iZ[(size_t)b*NPT + t*16];
    uint4 o0, o1;
    const u32 in[8] = {a0.x, a0.y, a0.z, a0.w, a1.x, a1.y, a1.z, a1.w};
    u32 outw[8];
    #pragma unroll
    for (int j = 0; j < 8; j++) {
        const float lo = __uint_as_float(in[j] << 16) * zp[2*j];
        const float hi = __uint_as_float(in[j] & 0xffff0000u) * zp[2*j+1];
        outw[j] = pack_trunc(lo, hi);
    }
    o0 = make_uint4(outw[0], outw[1], outw[2], outw[3]);
    o1 = make_uint4(outw[4], outw[5], outw[6], outw[7]);
    *(uint4*)&vn[base]     = o0;
    *(uint4*)&vn[base + 8] = o1;
}

// PV: o[c][m] = sum_n vn[c][n] * pT[m][n]; pure streaming GEMM, no LDS,
// no barriers. Block 256 = 4 waves (2 ci x 2 mi of 32x32 tiles), 64c x 64m
// per block. grid 1024 flat (b=id&3), block 256. out = acc + x.
__global__ __launch_bounds__(256, 4) void pv_kernel(
    const u16* __restrict__ vn, const u16* __restrict__ pT,
    const float* __restrict__ x, float* __restrict__ out)
{
    const int t = threadIdx.x;
    const int w = t >> 6, l = t & 63, l5 = l >> 5, lm = l & 31;
    const int mi = w & 1, ci = w >> 1;
    const int id = blockIdx.x;          // 0..1023
    const int b  = id & 3;
    const int ct = (id >> 2) & 3;
    const int mt = id >> 4;             // 0..63
    const int c0 = ct*64 + ci*32;
    const int m0 = mt*64 + mi*32;

    const u16* va_p = &vn[((size_t)(b*C_IN + c0 + lm))*NPT + 8*l5];
    const u16* pb_p = &pT[((size_t)b*NPT + m0 + lm)*NPT + 8*l5];

    f32x16 acc;
    #pragma unroll
    for (int r = 0; r < 16; r++) acc[r] = 0.f;

    for (int n = 0; n < NPT; n += 64) {
        #pragma unroll
        for (int kk = 0; kk < 4; kk++) {
            const bf16x8 va = *(const bf16x8*)(va_p + n + 16*kk);
            const bf16x8 pb = *(const bf16x8*)(pb_p + n + 16*kk);
            acc = MFMA3216(va, pb, acc);
        }
    }

    #pragma unroll
    for (int r = 0; r < 16; r++) {
        const int c = c0 + (r & 3) + 8*(r >> 2) + 4*l5;
        const size_t o = ((size_t)(b*C_IN + c))*NPT + m0 + lm;
        out[o] = acc[r] + x[o];
    }
}

// ===========================================================================
// FALLBACK PATH (R6, verified): stats -> merge -> attn
// ===========================================================================
__global__ __launch_bounds__(256) void stats_kernel(
    const u16* __restrict__ qT, const u16* __restrict__ kT,
    float* __restrict__ psum)
{
    const int t = threadIdx.x;
    const int w = t >> 6, l = t & 63, q = l >> 4, c16 = l & 15;
    const int ms = blockIdx.x, nt = blockIdx.y, b = blockIdx.z;
    const int nb = nt*64 + 16*w;

    const bf16x8* qp = (const bf16x8*)&qT[((size_t)b*NPT + nb + c16)*CQD + 8*q];
    const bf16x8 aq0 = qp[0];
    const bf16x8 aq1 = qp[4];

    float rz[4] = {0.f, 0.f, 0.f, 0.f};

    for (int m0 = ms*1024; m0 < ms*1024 + 1024; m0 += 64) {
        f32x4 s[4];
        #pragma unroll
        for (int mj = 0; mj < 4; mj++) {
            const bf16x8* kp = (const bf16x8*)&kT[((size_t)b*NPT + m0 + 16*mj + c16)*CQD + 8*q];
            f32x4 a = {0.f, 0.f, 0.f, 0.f};
            a = MFMA32(aq0, kp[0], a);
            a = MFMA32(aq1, kp[4], a);
            s[mj] = a;
        }
        #pragma unroll
        for (int r = 0; r < 4; r++) {
            rz[r] += EXP2F(s[0][r]*L2E) + EXP2F(s[1][r]*L2E)
                   + EXP2F(s[2][r]*L2E) + EXP2F(s[3][r]*L2E);
        }
    }
    #pragma unroll
    for (int r = 0; r < 4; r++) {
        float Z = rz[r];
        #pragma unroll
        for (int d = 1; d < 16; d <<= 1) Z += __shfl_xor(Z, d, 64);
        if (c16 == 0)
            psum[((size_t)(b*4 + ms))*NPT + nb + 4*q + r] = Z;
    }
}

__global__ void merge_kernel(const float* __restrict__ psum, float* __restrict__ Lrow)
{
    const int g = blockIdx.x*256 + threadIdx.x;
    const int b = g >> 12;
    const int n = g & 4095;
    float Z = 0.f;
    #pragma unroll
    for (int s = 0; s < 4; s++) Z += psum[((size_t)(b*4+s))*NPT + n];
    Lrow[(size_t)b*NPT + n] = __log2f(Z);
}

__global__ __launch_bounds__(256, 4) void attn_kernel(
    const u16* __restrict__ qT, const u16* __restrict__ kT, const u16* __restrict__ vbf,
    const float* __restrict__ Lrow, const float* __restrict__ gamma,
    const float* __restrict__ x, float* __restrict__ out)
{
    __shared__ uint2 p_l[2][1088];

    const int t = threadIdx.x;
    const int w = t >> 6, l = t & 63, q = l >> 4, c16 = l & 15;

    const int id   = blockIdx.x;
    const int pair = ((id & 7) << 1) | ((id >> 9) & 1);
    const int mt   = (id >> 3) & 63;
    const int b    = pair >> 2, cs = pair & 3;
    const int m0   = mt * 64;

    bf16x8 kf[4][2];
    #pragma unroll
    for (int mj = 0; mj < 4; mj++) {
        const bf16x8* kp = (const bf16x8*)&kT[((size_t)b*NPT + m0 + 16*mj + c16)*CQD + 8*q];
        kf[mj][0] = kp[0];
        kf[mj][1] = kp[4];
    }

    f32x4 acc[4];
    #pragma unroll
    for (int mj = 0; mj < 4; mj++) acc[mj] = (f32x4){0.f, 0.f, 0.f, 0.f};

    const u16*  qrow = &qT[((size_t)b*NPT + 16*w + c16)*CQD + 8*q];
    const float* Lb  = &Lrow[(size_t)b*NPT + 16*w + 4*q];
    const u16*  vrow = &vbf[((size_t)(b*C_IN + cs*64 + 16*w + c16))*NPT + 8*q];

    const int Uw  = (w*16 + q*4)*17 + c16;
    const int Ur0 = ((q>>1)*16 + (q&1)*8)*17 + c16;
    const int Ur1 = Ur0 + 32*17;

    bf16x8 qa0 = *(const bf16x8*)qrow;
    bf16x8 qa1 = *(const bf16x8*)(qrow + 32);

    int buf = 0;
    for (int nt = 0; nt < 64; nt++) {
        const int n0 = nt * 64;

        f32x4 s[4];
        #pragma unroll
        for (int mj = 0; mj < 4; mj++) {
            f32x4 a = {0.f, 0.f, 0.f, 0.f};
            a = MFMA32(qa0, kf[mj][0], a);
            a = MFMA32(qa1, kf[mj][1], a);
            s[mj] = a;
        }
        if (nt < 63) {
            qa0 = *(const bf16x8*)(qrow + (size_t)(n0 + 64)*CQD);
            qa1 = *(const bf16x8*)(qrow + (size_t)(n0 + 64)*CQD + 32);
        }
        const bf16x8 va0 = *(const bf16x8*)(vrow + n0);
        const bf16x8 va1 = *(const bf16x8*)(vrow + n0 + 32);

        const float4 Lr = *(const float4*)(Lb + n0);

        #pragma unroll
        for (int mj = 0; mj < 4; mj++) {
            const float p0 = EXP2F(s[mj][0]*L2E - Lr.x);
            const float p1 = EXP2F(s[mj][1]*L2E - Lr.y);
            const float p2 = EXP2F(s[mj][2]*L2E - Lr.z);
            const float p3 = EXP2F(s[mj][3]*L2E - Lr.w);
            uint2 u;
            u.x = pack_trunc(p0, p1);
            u.y = pack_trunc(p2, p3);
            p_l[buf][Uw + mj*17] = u;
        }
        __syncthreads();

        #pragma unroll
        for (int mj = 0; mj < 4; mj++) {
            const uint2 a0 = p_l[buf][Ur0 + mj*17];
            const uint2 a1 = p_l[buf][Ur0 + mj*17 + 68];
            const uint2 b0 = p_l[buf][Ur1 + mj*17];
            const uint2 b1 = p_l[buf][Ur1 + mj*17 + 68];
            uint4 fa = make_uint4(a0.x, a0.y, a1.x, a1.y);
            uint4 fb = make_uint4(b0.x, b0.y, b1.x, b1.y);
            acc[mj] = MFMA32(va0, *(bf16x8*)&fa, acc[mj]);
            acc[mj] = MFMA32(va1, *(bf16x8*)&fb, acc[mj]);
        }
        buf ^= 1;
    }

    const float g = gamma[0];
    #pragma unroll
    for (int mj = 0; mj < 4; mj++)
        #pragma unroll
        for (int r = 0; r < 4; r++) {
            const size_t o = ((size_t)(b*C_IN + cs*64 + 16*w + 4*q + r))*NPT
                           + m0 + 16*mj + c16;
            out[o] = g*acc[mj][r] + x[o];
        }
}

// ---------------------------------------------------------------------------
extern "C" void kernel_launch(void* const* d_in, const int* in_sizes, int n_in,
                              void* d_out, int out_size, void* d_ws, size_t ws_size,
                              hipStream_t stream)
{
    const float* x     = (const float*)d_in[0];
    const float* wq    = (const float*)d_in[1];
    const float* bq    = (const float*)d_in[2];
    const float* wk    = (const float*)d_in[3];
    const float* bk    = (const float*)d_in[4];
    const float* wv    = (const float*)d_in[5];
    const float* bv    = (const float*)d_in[6];
    const float* gamma = (const float*)d_in[7];
    float* out = (float*)d_out;

    u16* qT  = (u16*)d_ws;                              // 2 MB
    u16* kT  = qT  + (size_t)NB*NPT*CQD;                // 2 MB
    u16* vbf = kT  + (size_t)NB*NPT*CQD;                // 8 MB
    u16* wbf = vbf + (size_t)NB*C_IN*NPT;               // 192 KB
    float* bias = (float*)(wbf + 384*256);              // 1.5 KB

    // split-path layout
    float* Zpart = bias + 384;                          // 4*8*4096 f = 512 KB
    float* iZ    = Zpart + (size_t)NB*8*NPT;            // 64 KB
    u16*   vn    = (u16*)(iZ + (size_t)NB*NPT);         // 8 MB
    u16*   pT    = vn + (size_t)NB*C_IN*NPT;            // 128 MB
    const size_t need = (size_t)((char*)(pT + (size_t)NB*NPT*NPT) - (char*)d_ws);

    if (ws_size >= need) {
        prep_kernel<<<dim3(386), 256, 0, stream>>>(wq, bq, wk, bk, wv, bv, wbf, bias, L2E);
        proj_kernel<<<dim3(NPT/32, NB), 512, 0, stream>>>(x, wbf, bias, qT, kT, vbf);
        score_kernel<<<dim3(1024), 256, 0, stream>>>(qT, kT, Zpart, pT);
        iz_kernel<<<dim3(64), 256, 0, stream>>>(Zpart, gamma, iZ);
        vn_kernel<<<dim3(1024), 256, 0, stream>>>(vbf, iZ, vn);
        pv_kernel<<<dim3(1024), 256, 0, stream>>>(vn, pT, x, out);
    } else {
        // fallback (R6-verified): psum/Lrow reuse the split-scratch region
        float* psum = Zpart;                            // 4*4*4096 f
        float* Lrow = psum + (size_t)NB*4*NPT;
        prep_kernel<<<dim3(386), 256, 0, stream>>>(wq, bq, wk, bk, wv, bv, wbf, bias, 1.0f);
        proj_kernel<<<dim3(NPT/32, NB), 512, 0, stream>>>(x, wbf, bias, qT, kT, vbf);
        stats_kernel<<<dim3(4, NPT/64, NB), 256, 0, stream>>>(qT, kT, psum);
        merge_kernel<<<dim3(64), 256, 0, stream>>>(psum, Lrow);
        attn_kernel<<<dim3(1024), 256, 0, stream>>>(qT, kT, vbf, Lrow, gamma, x, out);
    }
}